// Round 17
// baseline (244.671 us; speedup 1.0000x reference)
//
#include <hip/hip_runtime.h>
#include <hip/hip_bf16.h>
#include <math.h>

// Problem constants
#define NB 32768   // batch
#define NH 256     // hidden = nsync
#define NI 128     // input
// out layout (f32): h[8388608] | alpha[8388608] | beta[8388608] | last[1]

typedef __attribute__((ext_vector_type(8))) short short8;  // 8 x bf16 mfma frag
typedef __attribute__((ext_vector_type(4))) float f32x4;   // mfma accum

__device__ __forceinline__ float b2f(unsigned int u) {
    union { float f; unsigned int i; } v; v.i = (u & 0xffffu) << 16; return v.f;
}
__device__ __forceinline__ unsigned short f2b(float f) {
    union { float f; unsigned int i; } v; v.f = f;
    unsigned int x = v.i;
    return (unsigned short)((x + 0x7fffu + ((x >> 16) & 1u)) >> 16);
}
__device__ __forceinline__ void unpack8(uint4 v, float* o) {
    o[0]=b2f(v.x); o[1]=b2f(v.x>>16);
    o[2]=b2f(v.y); o[3]=b2f(v.y>>16);
    o[4]=b2f(v.z); o[5]=b2f(v.z>>16);
    o[6]=b2f(v.w); o[7]=b2f(v.w>>16);
}
__device__ __forceinline__ uint4 pack8(const float* f) {
    uint4 r;
    r.x = (unsigned)f2b(f[0]) | ((unsigned)f2b(f[1])<<16);
    r.y = (unsigned)f2b(f[2]) | ((unsigned)f2b(f[3])<<16);
    r.z = (unsigned)f2b(f[4]) | ((unsigned)f2b(f[5])<<16);
    r.w = (unsigned)f2b(f[6]) | ((unsigned)f2b(f[7])<<16);
    return r;
}

// ---------------------------------------------------------------------------
// k_winit: W fragment-major + rs + zero both norm arrays. 81 blocks.
// ---------------------------------------------------------------------------
__global__ __launch_bounds__(256) void k_winit(const float* __restrict__ Wf,
                                               const float* __restrict__ Wm,
                                               const float* __restrict__ r_param,
                                               unsigned short* __restrict__ wsW,
                                               float* __restrict__ rs,
                                               float* __restrict__ n_spec,
                                               float* __restrict__ n_fb) {
    int b = blockIdx.x, tid = threadIdx.x;
    if (b < 80) {
        int gt = b * 256 + tid;                // 0..20479
        int s = gt >> 10, rem = gt & 1023;
        int n = rem >> 2, q = rem & 3;
        float vals[8];
        #pragma unroll
        for (int j = 0; j < 8; ++j) {
            int kg = s * 32 + q * 8 + j;       // global K index 0..639
            vals[j] = (kg < 384) ? Wf[n * 384 + kg] : Wm[n * 256 + (kg - 384)];
        }
        *(uint4*)(wsW + s * 8192 + (q * 256 + n) * 8) = pack8(vals);
    } else {
        rs[tid] = 1.0f / (1.0f + expf(-r_param[tid]));
        if (tid < 8) { n_spec[tid] = 0.0f; n_fb[tid] = 0.0f; }
    }
}

// ---------------------------------------------------------------------------
// phase-B helpers (named-register state; all forceinline)
// ---------------------------------------------------------------------------
__device__ __forceinline__ float bcol(int cj, float& al, float bt,
        const unsigned short* sH, int prow, unsigned pswz,
        const int* pIdx, const float* rsL) {
    int pr = pIdx[cj];
    float hl = b2f(*(const unsigned short*)((const char*)sH +
               (((unsigned)(prow * 512 + (pr & 0xffff) * 2)) ^ pswz)));
    float hr = b2f(*(const unsigned short*)((const char*)sH +
               (((unsigned)(prow * 512 + (pr >> 16) * 2)) ^ pswz)));
    al = rsL[cj] * al + hl * hr;
    return al * rsqrtf(bt);
}

__device__ __forceinline__ void bchunk(int K, float4& AL, float4& BT,
        unsigned short* sS, const unsigned short* sH, int tid, int prow,
        unsigned pswz, const int* pIdx, const float* rsL) {
    int c0 = (tid & 7) * 4 + K * 32;
    BT.x = rsL[c0 + 0] * BT.x + 1.0f;        // exact reference beta recurrence
    BT.y = rsL[c0 + 1] * BT.y + 1.0f;
    BT.z = rsL[c0 + 2] * BT.z + 1.0f;
    BT.w = rsL[c0 + 3] * BT.w + 1.0f;
    float s0 = bcol(c0 + 0, AL.x, BT.x, sH, prow, pswz, pIdx, rsL);
    float s1 = bcol(c0 + 1, AL.y, BT.y, sH, prow, pswz, pIdx, rsL);
    float s2 = bcol(c0 + 2, AL.z, BT.z, sH, prow, pswz, pIdx, rsL);
    float s3 = bcol(c0 + 3, AL.w, BT.w, sH, prow, pswz, pIdx, rsL);
    uint2 pk;
    pk.x = (unsigned)f2b(s0) | ((unsigned)f2b(s1) << 16);
    pk.y = (unsigned)f2b(s2) | ((unsigned)f2b(s3) << 16);
    *(uint2*)((char*)sS + (((unsigned)(prow * 512 + c0 * 2)) ^ pswz)) = pk;
}

__device__ __forceinline__ uint2 packbx(f32x4 a, float bias) {
    uint2 r;
    r.x = (unsigned)f2b(a[0] + bias) | ((unsigned)f2b(a[1] + bias) << 16);
    r.y = (unsigned)f2b(a[2] + bias) | ((unsigned)f2b(a[3] + bias) << 16);
    return r;
}

// epilogue for one C-fragment: hu + fused speculative h update (factor 2)
__device__ __forceinline__ float epifrag(int M, int N, f32x4 av, uint2 bx,
        unsigned short* sH, int lq, int lrow, int wave, float An, float inv_tau) {
    float bxf[4] = { b2f(bx.x), b2f(bx.x >> 16), b2f(bx.y), b2f(bx.y >> 16) };
    float ts = 0.0f;
    #pragma unroll
    for (int r = 0; r < 4; ++r) {
        int row = M * 16 + lq * 4 + r;
        int col = wave * 64 + N * 16 + lrow;
        unsigned byte = ((unsigned)(row * 512 + col * 2)) ^ ((unsigned)((row & 7) << 4));
        unsigned short* p16 = (unsigned short*)((char*)sH + byte);
        float arg = av[r] + bxf[r];
        float s = __sinf(arg);
        float fv = s * s;
        float hv = b2f(*p16);
        float dh = -hv * (inv_tau + fv) + An * fv;
        float huv = 0.1f * dh;
        *p16 = f2b(hv + 2.0f * huv);
        ts += fabsf(huv);
    }
    return ts;
}

// ---------------------------------------------------------------------------
// k_spec: SPECULATIVE full recurrence (no grid sync, factor=2 all 6 steps).
// r16 post-mortem: GEMM staging scheme is NOT the limiter (3 schemes, same
// time at 2 blk/CU). This round trades LDS for OCCUPANCY: W read directly
// from L2 (r9-proven loop, 84 VGPR), LDS 66.5->34.3KB => 4 blocks/CU,
// 16 waves/CU to cover the phase-B/epilogue scalar-LDS latency.
// ---------------------------------------------------------------------------
__global__ __launch_bounds__(256, 4) void k_spec(
        const float* __restrict__ x, const float* __restrict__ h0,
        const float* __restrict__ alpha0, const float* __restrict__ beta0,
        const unsigned short* __restrict__ wsW, const float* __restrict__ rs,
        const float* __restrict__ bfv, const float* __restrict__ tau,
        const float* __restrict__ Aparam,
        const int* __restrict__ idxl, const int* __restrict__ idxr,
        float* __restrict__ norms_spec, float* __restrict__ out) {
    __shared__ unsigned short sH[32 * 256];   // 16KB h state (swizzled)
    __shared__ unsigned short sS[32 * 256];   // 16KB x-stage / sync
    __shared__ int   pIdx[256];
    __shared__ float rsL[256];
    __shared__ float red[4];

    const int tid = threadIdx.x, bid = blockIdx.x;
    const int r0 = bid * 32;

    rsL[tid]  = rs[tid];
    pIdx[tid] = (idxl[tid] & 0xffff) | (idxr[tid] << 16);

    const int prow = tid >> 3;
    const unsigned pswz = (unsigned)((prow & 7) << 4);
    const int cbase = (r0 + prow) * 256 + (tid & 7) * 4;

    // h0 -> sH (bf16, swizzled, 512B row stride)
    #pragma unroll
    for (int k = 0; k < 4; ++k) {
        int c = (tid & 7) * 8 + k * 64;
        float4 v0 = *(const float4*)(h0 + (r0 + prow) * 256 + c);
        float4 v1 = *(const float4*)(h0 + (r0 + prow) * 256 + c + 4);
        float vf[8] = {v0.x, v0.y, v0.z, v0.w, v1.x, v1.y, v1.z, v1.w};
        *(uint4*)((char*)sH + (((unsigned)(prow * 512 + c * 2)) ^ pswz)) = pack8(vf);
    }
    // alpha0 -> 8 named float4 (cols cbase + k*32)
    float4 aA = *(const float4*)(alpha0 + cbase + 0 * 32);
    float4 aB = *(const float4*)(alpha0 + cbase + 1 * 32);
    float4 aC = *(const float4*)(alpha0 + cbase + 2 * 32);
    float4 aD = *(const float4*)(alpha0 + cbase + 3 * 32);
    float4 aE = *(const float4*)(alpha0 + cbase + 4 * 32);
    float4 aF = *(const float4*)(alpha0 + cbase + 5 * 32);
    float4 aG = *(const float4*)(alpha0 + cbase + 6 * 32);
    float4 aH = *(const float4*)(alpha0 + cbase + 7 * 32);
    // beta0 -> 8 named float4 (exact f32 state)
    float4 bA = *(const float4*)(beta0 + cbase + 0 * 32);
    float4 bB = *(const float4*)(beta0 + cbase + 1 * 32);
    float4 bC = *(const float4*)(beta0 + cbase + 2 * 32);
    float4 bD = *(const float4*)(beta0 + cbase + 3 * 32);
    float4 bE = *(const float4*)(beta0 + cbase + 4 * 32);
    float4 bF = *(const float4*)(beta0 + cbase + 5 * 32);
    float4 bG = *(const float4*)(beta0 + cbase + 6 * 32);
    float4 bH = *(const float4*)(beta0 + cbase + 7 * 32);
    // x tile -> sS (bf16, 32x128, 256B row stride)
    #pragma unroll
    for (int k = 0; k < 4; ++k) {
        int c = (tid & 7) * 4 + k * 32;
        float4 v = *(const float4*)(x + (r0 + prow) * 128 + c);
        uint2 pk;
        pk.x = (unsigned)f2b(v.x) | ((unsigned)f2b(v.y) << 16);
        pk.y = (unsigned)f2b(v.z) | ((unsigned)f2b(v.w) << 16);
        *(uint2*)((char*)sS + (((unsigned)(prow * 256 + c * 2)) ^ pswz)) = pk;
    }
    __syncthreads();

    // ---- MFMA geometry
    const int wave = tid >> 6, lane = tid & 63, lrow = lane & 15, lq = lane >> 4;
    const unsigned aswz = (unsigned)((lrow & 7) << 4);
    const int fragoff = (lq * 256 + wave * 64 + lrow) * 8;   // global fragment-major

    // ---- basex GEMM -> 8 named uint2 fragments (W direct from L2, one-shot)
    uint2 bx00, bx01, bx02, bx03, bx10, bx11, bx12, bx13;
    {
        f32x4 acc[2][4];
        #pragma unroll
        for (int m = 0; m < 2; ++m)
            #pragma unroll
            for (int n = 0; n < 4; ++n) { f32x4 z = {0.f,0.f,0.f,0.f}; acc[m][n] = z; }
        #pragma unroll
        for (int kk = 0; kk < 4; ++kk) {
            short8 bfr[4];
            #pragma unroll
            for (int n = 0; n < 4; ++n)
                bfr[n] = *(const short8*)(wsW + kk * 8192 + fragoff + n * 128);
            short8 a[2];
            int kb = (kk * 32 + lq * 8) * 2;
            #pragma unroll
            for (int m = 0; m < 2; ++m)
                a[m] = *(const short8*)((const char*)sS +
                        (((unsigned)((m * 16 + lrow) * 256 + kb)) ^ aswz));
            #pragma unroll
            for (int m = 0; m < 2; ++m)
                #pragma unroll
                for (int n = 0; n < 4; ++n)
                    acc[m][n] = __builtin_amdgcn_mfma_f32_16x16x32_bf16(a[m], bfr[n], acc[m][n], 0, 0, 0);
        }
        float bias0 = bfv[wave * 64 + 0 * 16 + lrow];
        float bias1 = bfv[wave * 64 + 1 * 16 + lrow];
        float bias2 = bfv[wave * 64 + 2 * 16 + lrow];
        float bias3 = bfv[wave * 64 + 3 * 16 + lrow];
        bx00 = packbx(acc[0][0], bias0); bx01 = packbx(acc[0][1], bias1);
        bx02 = packbx(acc[0][2], bias2); bx03 = packbx(acc[0][3], bias3);
        bx10 = packbx(acc[1][0], bias0); bx11 = packbx(acc[1][1], bias1);
        bx12 = packbx(acc[1][2], bias2); bx13 = packbx(acc[1][3], bias3);
    }
    float Areg[4];
    #pragma unroll
    for (int n = 0; n < 4; ++n) Areg[n] = Aparam[wave * 64 + n * 16 + lrow];
    const float inv_tau = 1.0f / log1pf(expf(tau[0]));
    __syncthreads();   // sS (x) consumed

    const unsigned short* wstep = wsW + 4 * 8192;   // slices 4..19

    for (int t = 0; t < 6; ++t) {
        // phase B: alpha/beta recurrence + sync -> sS (named-reg state)
        bchunk(0, aA, bA, sS, sH, tid, prow, pswz, pIdx, rsL);
        bchunk(1, aB, bB, sS, sH, tid, prow, pswz, pIdx, rsL);
        bchunk(2, aC, bC, sS, sH, tid, prow, pswz, pIdx, rsL);
        bchunk(3, aD, bD, sS, sH, tid, prow, pswz, pIdx, rsL);
        bchunk(4, aE, bE, sS, sH, tid, prow, pswz, pIdx, rsL);
        bchunk(5, aF, bF, sS, sH, tid, prow, pswz, pIdx, rsL);
        bchunk(6, aG, bG, sS, sH, tid, prow, pswz, pIdx, rsL);
        bchunk(7, aH, bH, sS, sH, tid, prow, pswz, pIdx, rsL);
        __syncthreads();   // sync tile visible

        // GEMM: [h | sync] (32x512) @ [Wfh|Wm]^T; W direct from L2 (r9 loop)
        f32x4 acc[2][4];
        #pragma unroll
        for (int m = 0; m < 2; ++m)
            #pragma unroll
            for (int n = 0; n < 4; ++n) { f32x4 z = {0.f,0.f,0.f,0.f}; acc[m][n] = z; }

        #pragma unroll 1
        for (int kk = 0; kk < 16; ++kk) {
            short8 bfr[4];
            #pragma unroll
            for (int n = 0; n < 4; ++n)
                bfr[n] = *(const short8*)(wstep + kk * 8192 + fragoff + n * 128);
            const char* srcA = (kk < 8) ? (const char*)sH : (const char*)sS;
            int kb = ((kk & 7) * 32 + lq * 8) * 2;
            short8 a0 = *(const short8*)(srcA + (((unsigned)((0 * 16 + lrow) * 512 + kb)) ^ aswz));
            short8 a1 = *(const short8*)(srcA + (((unsigned)((1 * 16 + lrow) * 512 + kb)) ^ aswz));
            acc[0][0] = __builtin_amdgcn_mfma_f32_16x16x32_bf16(a0, bfr[0], acc[0][0], 0, 0, 0);
            acc[0][1] = __builtin_amdgcn_mfma_f32_16x16x32_bf16(a0, bfr[1], acc[0][1], 0, 0, 0);
            acc[0][2] = __builtin_amdgcn_mfma_f32_16x16x32_bf16(a0, bfr[2], acc[0][2], 0, 0, 0);
            acc[0][3] = __builtin_amdgcn_mfma_f32_16x16x32_bf16(a0, bfr[3], acc[0][3], 0, 0, 0);
            acc[1][0] = __builtin_amdgcn_mfma_f32_16x16x32_bf16(a1, bfr[0], acc[1][0], 0, 0, 0);
            acc[1][1] = __builtin_amdgcn_mfma_f32_16x16x32_bf16(a1, bfr[1], acc[1][1], 0, 0, 0);
            acc[1][2] = __builtin_amdgcn_mfma_f32_16x16x32_bf16(a1, bfr[2], acc[1][2], 0, 0, 0);
            acc[1][3] = __builtin_amdgcn_mfma_f32_16x16x32_bf16(a1, bfr[3], acc[1][3], 0, 0, 0);
        }
        __syncthreads();   // all GEMM reads of sH done before epilogue rewrites it

        // epilogue: hu + fused speculative h update, norm partial
        float tsum = 0.0f;
        tsum += epifrag(0, 0, acc[0][0], bx00, sH, lq, lrow, wave, Areg[0], inv_tau);
        tsum += epifrag(0, 1, acc[0][1], bx01, sH, lq, lrow, wave, Areg[1], inv_tau);
        tsum += epifrag(0, 2, acc[0][2], bx02, sH, lq, lrow, wave, Areg[2], inv_tau);
        tsum += epifrag(0, 3, acc[0][3], bx03, sH, lq, lrow, wave, Areg[3], inv_tau);
        tsum += epifrag(1, 0, acc[1][0], bx10, sH, lq, lrow, wave, Areg[0], inv_tau);
        tsum += epifrag(1, 1, acc[1][1], bx11, sH, lq, lrow, wave, Areg[1], inv_tau);
        tsum += epifrag(1, 2, acc[1][2], bx12, sH, lq, lrow, wave, Areg[2], inv_tau);
        tsum += epifrag(1, 3, acc[1][3], bx13, sH, lq, lrow, wave, Areg[3], inv_tau);
        #pragma unroll
        for (int d = 32; d >= 1; d >>= 1) tsum += __shfl_down(tsum, d);
        if (lane == 0) red[wave] = tsum;
        __syncthreads();   // red + sH updates visible for next phase B
        if (tid == 0) atomicAdd(&norms_spec[t], red[0] + red[1] + red[2] + red[3]);
    }

    // ---- speculative outputs (f32); valid iff no break would have fired
    #pragma unroll
    for (int k = 0; k < 4; ++k) {
        int c = (tid & 7) * 8 + k * 64;
        uint4 hv = *(const uint4*)((const char*)sH + (((unsigned)(prow * 512 + c * 2)) ^ pswz));
        float hf[8];
        unpack8(hv, hf);
        int off = (r0 + prow) * 256 + c;
        *(float4*)(out + off)     = make_float4(hf[0], hf[1], hf[2], hf[3]);
        *(float4*)(out + off + 4) = make_float4(hf[4], hf[5], hf[6], hf[7]);
    }
    *(float4*)(out + 8388608 + cbase + 0 * 32) = aA;
    *(float4*)(out + 8388608 + cbase + 1 * 32) = aB;
    *(float4*)(out + 8388608 + cbase + 2 * 32) = aC;
    *(float4*)(out + 8388608 + cbase + 3 * 32) = aD;
    *(float4*)(out + 8388608 + cbase + 4 * 32) = aE;
    *(float4*)(out + 8388608 + cbase + 5 * 32) = aF;
    *(float4*)(out + 8388608 + cbase + 6 * 32) = aG;
    *(float4*)(out + 8388608 + cbase + 7 * 32) = aH;
    *(float4*)(out + 16777216 + cbase + 0 * 32) = bA;
    *(float4*)(out + 16777216 + cbase + 1 * 32) = bB;
    *(float4*)(out + 16777216 + cbase + 2 * 32) = bC;
    *(float4*)(out + 16777216 + cbase + 3 * 32) = bD;
    *(float4*)(out + 16777216 + cbase + 4 * 32) = bE;
    *(float4*)(out + 16777216 + cbase + 5 * 32) = bF;
    *(float4*)(out + 16777216 + cbase + 6 * 32) = bG;
    *(float4*)(out + 16777216 + cbase + 7 * 32) = bH;
    if (bid == 0 && tid == 0) out[25165824] = 5.0f;
}

// ---------------------------------------------------------------------------
// k_check: speculation valid iff no break at steps 3,4,5.
// ---------------------------------------------------------------------------
__global__ void k_check(const float* __restrict__ norms_spec, int* __restrict__ flag) {
    if (threadIdx.x == 0 && blockIdx.x == 0) {
        float thr = 0.01f * 8388608.0f;
        int ok = (norms_spec[3] >= thr) && (norms_spec[4] >= thr) && (norms_spec[5] >= thr);
        *flag = ok;
    }
}

// ===========================================================================
// FALLBACK (early-exit when *flag != 0): round-5 proven kernel set.
// ===========================================================================
struct StepCtl { bool run; bool upd; float factor; };
__device__ __forceinline__ StepCtl step_ctl(const float* norms, int t) {
    bool done = false, done_prev = false, brk_prev = false;
    for (int s = 0; s < t; ++s) {
        bool brk = false;
        if (!done) {
            float nm = norms[s] * (1.0f / 8388608.0f);
            brk = (s >= 3) && (nm < 0.01f);
        }
        if (s == t - 1) { done_prev = done; brk_prev = brk; }
        done = done || brk;
    }
    StepCtl c;
    c.upd = (t > 0) && !done_prev;
    c.factor = brk_prev ? 1.0f : 2.0f;
    c.run = !done;
    return c;
}

__global__ __launch_bounds__(256) void k_fbinit(const float* __restrict__ h0,
                                                const float* __restrict__ beta0,
                                                unsigned short* __restrict__ h_ws,
                                                unsigned short* __restrict__ b0b,
                                                const int* __restrict__ flag) {
    if (*flag) return;
    int b = blockIdx.x, tid = threadIdx.x;
    if (b < 4096) {
        int idx = b * 2048 + tid * 8;
        float4 v0 = *(const float4*)(h0 + idx), v1 = *(const float4*)(h0 + idx + 4);
        float vf[8] = {v0.x, v0.y, v0.z, v0.w, v1.x, v1.y, v1.z, v1.w};
        *(uint4*)(h_ws + idx) = pack8(vf);
    } else {
        int idx = (b - 4096) * 2048 + tid * 8;
        float4 v0 = *(const float4*)(beta0 + idx), v1 = *(const float4*)(beta0 + idx + 4);
        float vf[8] = {v0.x, v0.y, v0.z, v0.w, v1.x, v1.y, v1.z, v1.w};
        *(uint4*)(b0b + idx) = pack8(vf);
    }
}

__global__ __launch_bounds__(256, 4) void k_basex(const float* __restrict__ x,
                                                  const float* __restrict__ bfv,
                                                  const unsigned short* __restrict__ wsW,
                                                  unsigned short* __restrict__ basex,
                                                  const int* __restrict__ flag) {
    if (*flag) return;
    __shared__ unsigned short sX[32 * 128];
    const int tid = threadIdx.x, r0 = blockIdx.x * 32;
    const int prow = tid >> 3;
    const unsigned pswz = (unsigned)((prow & 7) << 4);

    #pragma unroll
    for (int k = 0; k < 4; ++k) {
        int c = (tid & 7) * 4 + k * 32;
        float4 v = *(const float4*)(x + (r0 + prow) * 128 + c);
        uint2 pk;
        pk.x = (unsigned)f2b(v.x) | ((unsigned)f2b(v.y) << 16);
        pk.y = (unsigned)f2b(v.z) | ((unsigned)f2b(v.w) << 16);
        *(uint2*)((char*)sX + (((unsigned)(prow * 256 + c * 2)) ^ pswz)) = pk;
    }
    __syncthreads();

    const int wave = tid >> 6, lane = tid & 63, lrow = lane & 15, lq = lane >> 4;
    const unsigned aswz = (unsigned)((lrow & 7) << 4);
    const int fragoff = (lq * 256 + wave * 64 + lrow) * 8;

    f32x4 acc[2][4];
    #pragma unroll
    for (int m = 0; m < 2; ++m)
        #pragma unroll
        for (int n = 0; n < 4; ++n) { f32x4 z = {0.f,0.f,0.f,0.f}; acc[m][n] = z; }

    #pragma unroll
    for (int kk = 0; kk < 4; ++kk) {
        short8 bfr[4];
        #pragma unroll
        for (int n = 0; n < 4; ++n)
            bfr[n] = *(const short8*)(wsW + kk * 8192 + fragoff + n * 128);
        short8 a[2];
        int kb = (kk * 32 + lq * 8) * 2;
        #pragma unroll
        for (int m = 0; m < 2; ++m)
            a[m] = *(const short8*)((const char*)sX +
                    (((unsigned)((m * 16 + lrow) * 256 + kb)) ^ aswz));
        #pragma unroll
        for (int m = 0; m < 2; ++m)
            #pragma unroll
            for (int n = 0; n < 4; ++n)
                acc[m][n] = __builtin_amdgcn_mfma_f32_16x16x32_bf16(a[m], bfr[n], acc[m][n], 0, 0, 0);
    }

    #pragma unroll
    for (int n = 0; n < 4; ++n) {
        int col = wave * 64 + n * 16 + lrow;
        float bias = bfv[col];
        #pragma unroll
        for (int m = 0; m < 2; ++m)
            #pragma unroll
            for (int r = 0; r < 4; ++r) {
                int row = m * 16 + lq * 4 + r;
                basex[(r0 + row) * 256 + col] = f2b(acc[m][n][r] + bias);
            }
    }
}

__global__ __launch_bounds__(256, 4) void k_step(int t,
        unsigned short* __restrict__ h_ws, unsigned short* __restrict__ hu,
        const unsigned short* __restrict__ basex, const unsigned short* __restrict__ b0b,
        const unsigned short* __restrict__ wsW, const float* __restrict__ rs,
        float* __restrict__ norms,
        const float* __restrict__ alpha0, float* __restrict__ alpha_io,
        const int* __restrict__ idxl, const int* __restrict__ idxr,
        const float* __restrict__ Aparam, const float* __restrict__ tau,
        const int* __restrict__ flag) {
    if (*flag) return;
    __shared__ unsigned short sH[32 * 256];
    __shared__ unsigned short sA[32 * 256];
    __shared__ int   pIdx[256];
    __shared__ float rsL[256], btP[256], btS[256];
    __shared__ float red[4];

    const int tid = threadIdx.x;
    const int r0 = blockIdx.x * 32;

    StepCtl ctl = step_ctl(norms, t);
    if (!ctl.run && !ctl.upd) return;

    {
        float rr = rs[tid];
        rsL[tid]  = rr;
        pIdx[tid] = (idxl[tid] & 0xffff) | (idxr[tid] << 16);
        float p = 1.0f, ssum = 0.0f;
        for (int u = 0; u <= t; ++u) { ssum += p; p *= rr; }
        btP[tid] = p; btS[tid] = ssum;
    }

    const int prow = tid >> 3;
    const unsigned pswz = (unsigned)((prow & 7) << 4);

    #pragma unroll
    for (int k = 0; k < 4; ++k) {
        int c = (tid & 7) * 8 + k * 64;
        int off = (r0 + prow) * 256 + c;
        uint4 hv = *(const uint4*)(h_ws + off);
        if (ctl.upd) {
            uint4 uv = *(const uint4*)(hu + off);
            float hf[8], uf[8], nf[8];
            unpack8(hv, hf); unpack8(uv, uf);
            #pragma unroll
            for (int j = 0; j < 8; ++j) nf[j] = hf[j] + ctl.factor * uf[j];
            hv = pack8(nf);
            *(uint4*)(h_ws + off) = hv;
        }
        *(uint4*)((char*)sH + (((unsigned)(prow * 512 + c * 2)) ^ pswz)) = hv;
    }
    if (!ctl.run) return;
    __syncthreads();

    #pragma unroll
    for (int k = 0; k < 8; ++k) {
        int c = (tid & 7) * 4 + k * 32;
        int off = (r0 + prow) * 256 + c;
        float4 av = (t == 0) ? *(const float4*)(alpha0 + off)
                             : *(const float4*)(alpha_io + off);
        uint2 b0v = *(const uint2*)(b0b + off);
        float bb[4] = {b2f(b0v.x), b2f(b0v.x >> 16), b2f(b0v.y), b2f(b0v.y >> 16)};
        float aa[4] = {av.x, av.y, av.z, av.w};
        float sy[4];
        #pragma unroll
        for (int j = 0; j < 4; ++j) {
            int cj = c + j;
            int pr = pIdx[cj];
            float hl = b2f(*(const unsigned short*)((const char*)sH +
                       (((unsigned)(prow * 512 + (pr & 0xffff) * 2)) ^ pswz)));
            float hr = b2f(*(const unsigned short*)((const char*)sH +
                       (((unsigned)(prow * 512 + (pr >> 16) * 2)) ^ pswz)));
            float a_new = rsL[cj] * aa[j] + hl * hr;
            aa[j] = a_new;
            float bt = btP[cj] * bb[j] + btS[cj];
            sy[j] = a_new / (sqrtf(bt) + 1e-6f);
        }
        *(float4*)(alpha_io + off) = make_float4(aa[0], aa[1], aa[2], aa[3]);
        uint2 pk;
        pk.x = (unsigned)f2b(sy[0]) | ((unsigned)f2b(sy[1]) << 16);
        pk.y = (unsigned)f2b(sy[2]) | ((unsigned)f2b(sy[3]) << 16);
        *(uint2*)((char*)sA + (((unsigned)(prow * 512 + c * 2)) ^ pswz)) = pk;
    }
    __syncthreads();

    const int wave = tid >> 6, lane = tid & 63, lrow = lane & 15, lq = lane >> 4;
    const unsigned aswz = (unsigned)((lrow & 7) << 4);
    const int fragoff = (lq * 256 + wave * 64 + lrow) * 8;
    const unsigned short* wstep = wsW + 4 * 8192;

    f32x4 acc[2][4];
    #pragma unroll
    for (int m = 0; m < 2; ++m)
        #pragma unroll
        for (int n = 0; n < 4; ++n) { f32x4 z = {0.f,0.f,0.f,0.f}; acc[m][n] = z; }

    #pragma unroll 1
    for (int kk = 0; kk < 16; ++kk) {
        short8 bfr[4];
        #pragma unroll
        for (int n = 0; n < 4; ++n)
            bfr[n] = *(const short8*)(wstep + kk * 8192 + fragoff + n * 128);
        const char* src = (kk < 8) ? (const char*)sH : (const char*)sA;
        int kb = ((kk & 7) * 32 + lq * 8) * 2;
        short8 a[2];
        #pragma unroll
        for (int m = 0; m < 2; ++m)
            a[m] = *(const short8*)(src + (((unsigned)((m * 16 + lrow) * 512 + kb)) ^ aswz));
        #pragma unroll
        for (int m = 0; m < 2; ++m)
            #pragma unroll
            for (int n = 0; n < 4; ++n)
                acc[m][n] = __builtin_amdgcn_mfma_f32_16x16x32_bf16(a[m], bfr[n], acc[m][n], 0, 0, 0);
    }

    const float inv_tau = 1.0f / log1pf(expf(tau[0]));
    float Areg[4];
    #pragma unroll
    for (int n = 0; n < 4; ++n) Areg[n] = Aparam[wave * 64 + n * 16 + lrow];
    float tsum = 0.0f;
    #pragma unroll
    for (int m = 0; m < 2; ++m)
        #pragma unroll
        for (int n = 0; n < 4; ++n) {
            int col = wave * 64 + n * 16 + lrow;
            #pragma unroll
            for (int r = 0; r < 4; ++r) {
                int row = m * 16 + lq * 4 + r;
                int off = (r0 + row) * 256 + col;
                float arg = acc[m][n][r] + b2f(basex[off]);
                float s = __sinf(arg);
                float fv = s * s;
                float hv = b2f(*(const unsigned short*)((const char*)sH +
                           (((unsigned)(row * 512 + col * 2)) ^ ((unsigned)((row & 7) << 4)))));
                float dh = -hv * (inv_tau + fv) + Areg[n] * fv;
                float huv = 0.1f * dh;
                hu[off] = f2b(huv);
                tsum += fabsf(huv);
            }
        }
    #pragma unroll
    for (int d = 32; d >= 1; d >>= 1) tsum += __shfl_down(tsum, d);
    if (lane == 0) red[wave] = tsum;
    __syncthreads();
    if (tid == 0) atomicAdd(&norms[t], red[0] + red[1] + red[2] + red[3]);
}

__global__ __launch_bounds__(256) void k_final(const unsigned short* __restrict__ h_ws,
                                               const unsigned short* __restrict__ hu,
                                               const unsigned short* __restrict__ b0b,
                                               const float* __restrict__ rs,
                                               const float* __restrict__ norms,
                                               float* __restrict__ out,
                                               const int* __restrict__ flag) {
    if (*flag) return;
    bool done = false, exec5 = false;
    int last = 0;
    float f5 = 2.0f;
    for (int s = 0; s < 6; ++s) {
        if (!done) {
            last = s;
            float nm = norms[s] * (1.0f / 8388608.0f);
            bool brk = (s >= 3) && (nm < 0.01f);
            if (s == 5) { exec5 = true; f5 = brk ? 1.0f : 2.0f; }
            done = done || brk;
        }
    }
    int n_exec = last + 1;

    int base = (blockIdx.x * 256 + threadIdx.x) * 16;
    #pragma unroll
    for (int c8 = 0; c8 < 2; ++c8) {
        int off = base + c8 * 8;
        uint4 hv = *(const uint4*)(h_ws + off);
        float hf[8];
        unpack8(hv, hf);
        if (exec5) {
            uint4 uv = *(const uint4*)(hu + off);
            float uf[8];
            unpack8(uv, uf);
            #pragma unroll
            for (int j = 0; j < 8; ++j) hf[j] += f5 * uf[j];
        }
        *(float4*)(out + off)     = make_float4(hf[0], hf[1], hf[2], hf[3]);
        *(float4*)(out + off + 4) = make_float4(hf[4], hf[5], hf[6], hf[7]);

        uint4 bv = *(const uint4*)(b0b + off);
        float bb[8];
        unpack8(bv, bb);
        int c0 = off & 255;
        float bo[8];
        #pragma unroll
        for (int j = 0; j < 8; ++j) {
            float rr = rs[c0 + j];
            float p = 1.0f, ss = 0.0f;
            for (int u = 0; u < n_exec; ++u) { ss += p; p *= rr; }
            bo[j] = p * bb[j] + ss;
        }
        *(float4*)(out + 16777216 + off)     = make_float4(bo[0], bo[1], bo[2], bo[3]);
        *(float4*)(out + 16777216 + off + 4) = make_float4(bo[4], bo[5], bo[6], bo[7]);
    }
    if (blockIdx.x == 0 && threadIdx.x == 0) out[25165824] = (float)last;
}

// ---------------------------------------------------------------------------
extern "C" void kernel_launch(void* const* d_in, const int* in_sizes, int n_in,
                              void* d_out, int out_size, void* d_ws, size_t ws_size,
                              hipStream_t stream) {
    const float* x      = (const float*)d_in[0];
    const float* h0     = (const float*)d_in[1];
    const float* alpha0 = (const float*)d_in[2];
    const float* beta0  = (const float*)d_in[3];
    const float* Wf     = (const float*)d_in[4];
    const float* bfv    = (const float*)d_in[5];
    const float* tau    = (const float*)d_in[6];
    const float* rparam = (const float*)d_in[7];
    const float* Aparam = (const float*)d_in[8];
    const float* Wm     = (const float*)d_in[9];
    const int* idxl     = (const int*)d_in[10];
    const int* idxr     = (const int*)d_in[11];

    char* ws = (char*)d_ws;
    unsigned short* h_ws   = (unsigned short*)(ws + 0);           // bf16 16.78MB (fallback)
    unsigned short* hu     = (unsigned short*)(ws + 16777216);    // bf16 16.78MB (fallback)
    unsigned short* basex  = (unsigned short*)(ws + 33554432);    // bf16 16.78MB (fallback)
    unsigned short* b0b    = (unsigned short*)(ws + 50331648);    // bf16 16.78MB (fallback)
    unsigned short* wsW    = (unsigned short*)(ws + 67108864);    // bf16 320KB
    float*          rs     = (float*)(ws + 67436544);             // f32 [256]
    float*          n_spec = (float*)(ws + 67437568);             // f32 [8]
    float*          n_fb   = (float*)(ws + 67437600);             // f32 [8]
    int*            flag   = (int*)(ws + 67437632);               // int

    float* out = (float*)d_out;
    float* alpha_io = out + 8388608;   // fallback writes alpha in place

    k_winit<<<81, 256, 0, stream>>>(Wf, Wm, rparam, wsW, rs, n_spec, n_fb);
    k_spec<<<1024, 256, 0, stream>>>(x, h0, alpha0, beta0, wsW, rs, bfv, tau,
                                     Aparam, idxl, idxr, n_spec, out);
    k_check<<<1, 64, 0, stream>>>(n_spec, flag);
    // fallback chain (early-exits when speculation verified)
    k_fbinit<<<8192, 256, 0, stream>>>(h0, beta0, h_ws, b0b, flag);
    k_basex<<<1024, 256, 0, stream>>>(x, bfv, wsW, basex, flag);
    for (int t = 0; t < 6; ++t)
        k_step<<<1024, 256, 0, stream>>>(t, h_ws, hu, basex, b0b, wsW, rs, n_fb,
                                         alpha0, alpha_io, idxl, idxr, Aparam, tau, flag);
    k_final<<<2048, 256, 0, stream>>>(h_ws, hu, b0b, rs, n_fb, out, flag);
}

// Round 18
// 197.416 us; speedup vs baseline: 1.2394x; 1.2394x over previous
//
#include <hip/hip_runtime.h>
#include <hip/hip_bf16.h>
#include <math.h>

// Problem constants
#define NB 32768   // batch
#define NH 256     // hidden = nsync
#define NI 128     // input
// out layout (f32): h[8388608] | alpha[8388608] | beta[8388608] | last[1]

typedef __attribute__((ext_vector_type(8))) short short8;  // 8 x bf16 mfma frag
typedef __attribute__((ext_vector_type(4))) float f32x4;   // mfma accum

__device__ __forceinline__ float b2f(unsigned int u) {
    union { float f; unsigned int i; } v; v.i = (u & 0xffffu) << 16; return v.f;
}
__device__ __forceinline__ unsigned short f2b(float f) {
    union { float f; unsigned int i; } v; v.f = f;
    unsigned int x = v.i;
    return (unsigned short)((x + 0x7fffu + ((x >> 16) & 1u)) >> 16);
}
__device__ __forceinline__ void unpack8(uint4 v, float* o) {
    o[0]=b2f(v.x); o[1]=b2f(v.x>>16);
    o[2]=b2f(v.y); o[3]=b2f(v.y>>16);
    o[4]=b2f(v.z); o[5]=b2f(v.z>>16);
    o[6]=b2f(v.w); o[7]=b2f(v.w>>16);
}
__device__ __forceinline__ uint4 pack8(const float* f) {
    uint4 r;
    r.x = (unsigned)f2b(f[0]) | ((unsigned)f2b(f[1])<<16);
    r.y = (unsigned)f2b(f[2]) | ((unsigned)f2b(f[3])<<16);
    r.z = (unsigned)f2b(f[4]) | ((unsigned)f2b(f[5])<<16);
    r.w = (unsigned)f2b(f[6]) | ((unsigned)f2b(f[7])<<16);
    return r;
}

// async global -> LDS 16B copy (wave-uniform base + lane*16; layout linear)
__device__ __forceinline__ void gload_lds16(const unsigned short* g, unsigned short* l) {
    __builtin_amdgcn_global_load_lds(
        (const __attribute__((address_space(1))) unsigned int*)(const void*)g,
        (__attribute__((address_space(3))) unsigned int*)(void*)l, 16, 0, 0);
}

// ---------------------------------------------------------------------------
// k_winit: W fragment-major + rs + zero both norm arrays. 81 blocks.
// ---------------------------------------------------------------------------
__global__ __launch_bounds__(256) void k_winit(const float* __restrict__ Wf,
                                               const float* __restrict__ Wm,
                                               const float* __restrict__ r_param,
                                               unsigned short* __restrict__ wsW,
                                               float* __restrict__ rs,
                                               float* __restrict__ n_spec,
                                               float* __restrict__ n_fb) {
    int b = blockIdx.x, tid = threadIdx.x;
    if (b < 80) {
        int gt = b * 256 + tid;                // 0..20479
        int s = gt >> 10, rem = gt & 1023;
        int n = rem >> 2, q = rem & 3;
        float vals[8];
        #pragma unroll
        for (int j = 0; j < 8; ++j) {
            int kg = s * 32 + q * 8 + j;       // global K index 0..639
            vals[j] = (kg < 384) ? Wf[n * 384 + kg] : Wm[n * 256 + (kg - 384)];
        }
        *(uint4*)(wsW + s * 8192 + (q * 256 + n) * 8) = pack8(vals);
    } else {
        rs[tid] = 1.0f / (1.0f + expf(-r_param[tid]));
        if (tid < 8) { n_spec[tid] = 0.0f; n_fb[tid] = 0.0f; }
    }
}

// ---------------------------------------------------------------------------
// phase-B helpers (named-register state; all forceinline)
// ---------------------------------------------------------------------------
__device__ __forceinline__ float bcol(int cj, float& al, float bt,
        const unsigned short* sH, int prow, unsigned pswz,
        const int* pIdx, const float* rsL) {
    int pr = pIdx[cj];
    float hl = b2f(*(const unsigned short*)((const char*)sH +
               (((unsigned)(prow * 512 + (pr & 0xffff) * 2)) ^ pswz)));
    float hr = b2f(*(const unsigned short*)((const char*)sH +
               (((unsigned)(prow * 512 + (pr >> 16) * 2)) ^ pswz)));
    al = rsL[cj] * al + hl * hr;
    return al * rsqrtf(bt);
}

__device__ __forceinline__ void bchunk(int K, float4& AL, float4& BT,
        unsigned short* sS, const unsigned short* sH, int tid, int prow,
        unsigned pswz, const int* pIdx, const float* rsL) {
    int c0 = (tid & 7) * 4 + K * 32;
    BT.x = rsL[c0 + 0] * BT.x + 1.0f;        // exact reference beta recurrence
    BT.y = rsL[c0 + 1] * BT.y + 1.0f;
    BT.z = rsL[c0 + 2] * BT.z + 1.0f;
    BT.w = rsL[c0 + 3] * BT.w + 1.0f;
    float s0 = bcol(c0 + 0, AL.x, BT.x, sH, prow, pswz, pIdx, rsL);
    float s1 = bcol(c0 + 1, AL.y, BT.y, sH, prow, pswz, pIdx, rsL);
    float s2 = bcol(c0 + 2, AL.z, BT.z, sH, prow, pswz, pIdx, rsL);
    float s3 = bcol(c0 + 3, AL.w, BT.w, sH, prow, pswz, pIdx, rsL);
    uint2 pk;
    pk.x = (unsigned)f2b(s0) | ((unsigned)f2b(s1) << 16);
    pk.y = (unsigned)f2b(s2) | ((unsigned)f2b(s3) << 16);
    *(uint2*)((char*)sS + (((unsigned)(prow * 512 + c0 * 2)) ^ pswz)) = pk;
}

__device__ __forceinline__ uint2 packbx(f32x4 a, float bias) {
    uint2 r;
    r.x = (unsigned)f2b(a[0] + bias) | ((unsigned)f2b(a[1] + bias) << 16);
    r.y = (unsigned)f2b(a[2] + bias) | ((unsigned)f2b(a[3] + bias) << 16);
    return r;
}

// epilogue for one C-fragment: hu + fused speculative h update (factor 2)
__device__ __forceinline__ float epifrag(int M, int N, f32x4 av, uint2 bx,
        unsigned short* sH, int lq, int lrow, int wave, float An, float inv_tau) {
    float bxf[4] = { b2f(bx.x), b2f(bx.x >> 16), b2f(bx.y), b2f(bx.y >> 16) };
    float ts = 0.0f;
    #pragma unroll
    for (int r = 0; r < 4; ++r) {
        int row = M * 16 + lq * 4 + r;
        int col = wave * 64 + N * 16 + lrow;
        unsigned byte = ((unsigned)(row * 512 + col * 2)) ^ ((unsigned)((row & 7) << 4));
        unsigned short* p16 = (unsigned short*)((char*)sH + byte);
        float arg = av[r] + bxf[r];
        float s = __sinf(arg);
        float fv = s * s;
        float hv = b2f(*p16);
        float dh = -hv * (inv_tau + fv) + An * fv;
        float huv = 0.1f * dh;
        *p16 = f2b(hv + 2.0f * huv);
        ts += fabsf(huv);
    }
    return ts;
}

// ---------------------------------------------------------------------------
// k_spec: SPECULATIVE full recurrence (no grid sync, factor=2 all 6 steps).
// W staged WAVE-PRIVATE: each wave async-copies its own 64-col stripe (4KB)
// of each slice into its private LDS dbuf -> ZERO barriers in the kk loop
// (sH/sS read-only there). Wave-level ordering via s_waitcnt vmcnt(0).
// Barriers per step: 16 -> 3. LDS 66KB -> 2 blocks/CU, VGPR cap 256.
// (r17 A/B confirmed: (256,4)=128-cap spills the 80-reg persistent state;
//  this (256,2) variant is the measured best of 5 structural variants.)
// ---------------------------------------------------------------------------
__global__ __launch_bounds__(256, 2) void k_spec(
        const float* __restrict__ x, const float* __restrict__ h0,
        const float* __restrict__ alpha0, const float* __restrict__ beta0,
        const unsigned short* __restrict__ wsW, const float* __restrict__ rs,
        const float* __restrict__ bfv, const float* __restrict__ tau,
        const float* __restrict__ Aparam,
        const int* __restrict__ idxl, const int* __restrict__ idxr,
        float* __restrict__ norms_spec, float* __restrict__ out) {
    __shared__ unsigned short sH[32 * 256];   // 16KB h state (swizzled)
    __shared__ unsigned short sS[32 * 256];   // 16KB x-stage / sync
    __shared__ unsigned short sW[4 * 4096];   // 32KB: 4 waves x 2 bufs x 2048 shorts
    __shared__ int   pIdx[256];
    __shared__ float rsL[256];
    __shared__ float red[4];

    const int tid = threadIdx.x, bid = blockIdx.x;
    const int r0 = bid * 32;

    rsL[tid]  = rs[tid];
    pIdx[tid] = (idxl[tid] & 0xffff) | (idxr[tid] << 16);

    const int prow = tid >> 3;
    const unsigned pswz = (unsigned)((prow & 7) << 4);
    const int cbase = (r0 + prow) * 256 + (tid & 7) * 4;

    // h0 -> sH (bf16, swizzled, 512B row stride)
    #pragma unroll
    for (int k = 0; k < 4; ++k) {
        int c = (tid & 7) * 8 + k * 64;
        float4 v0 = *(const float4*)(h0 + (r0 + prow) * 256 + c);
        float4 v1 = *(const float4*)(h0 + (r0 + prow) * 256 + c + 4);
        float vf[8] = {v0.x, v0.y, v0.z, v0.w, v1.x, v1.y, v1.z, v1.w};
        *(uint4*)((char*)sH + (((unsigned)(prow * 512 + c * 2)) ^ pswz)) = pack8(vf);
    }
    // alpha0 -> 8 named float4 (cols cbase + k*32)
    float4 aA = *(const float4*)(alpha0 + cbase + 0 * 32);
    float4 aB = *(const float4*)(alpha0 + cbase + 1 * 32);
    float4 aC = *(const float4*)(alpha0 + cbase + 2 * 32);
    float4 aD = *(const float4*)(alpha0 + cbase + 3 * 32);
    float4 aE = *(const float4*)(alpha0 + cbase + 4 * 32);
    float4 aF = *(const float4*)(alpha0 + cbase + 5 * 32);
    float4 aG = *(const float4*)(alpha0 + cbase + 6 * 32);
    float4 aH = *(const float4*)(alpha0 + cbase + 7 * 32);
    // beta0 -> 8 named float4 (exact f32 state)
    float4 bA = *(const float4*)(beta0 + cbase + 0 * 32);
    float4 bB = *(const float4*)(beta0 + cbase + 1 * 32);
    float4 bC = *(const float4*)(beta0 + cbase + 2 * 32);
    float4 bD = *(const float4*)(beta0 + cbase + 3 * 32);
    float4 bE = *(const float4*)(beta0 + cbase + 4 * 32);
    float4 bF = *(const float4*)(beta0 + cbase + 5 * 32);
    float4 bG = *(const float4*)(beta0 + cbase + 6 * 32);
    float4 bH = *(const float4*)(beta0 + cbase + 7 * 32);
    // x tile -> sS (bf16, 32x128, 256B row stride)
    #pragma unroll
    for (int k = 0; k < 4; ++k) {
        int c = (tid & 7) * 4 + k * 32;
        float4 v = *(const float4*)(x + (r0 + prow) * 128 + c);
        uint2 pk;
        pk.x = (unsigned)f2b(v.x) | ((unsigned)f2b(v.y) << 16);
        pk.y = (unsigned)f2b(v.z) | ((unsigned)f2b(v.w) << 16);
        *(uint2*)((char*)sS + (((unsigned)(prow * 256 + c * 2)) ^ pswz)) = pk;
    }
    __syncthreads();

    // ---- MFMA geometry
    const int wave = tid >> 6, lane = tid & 63, lrow = lane & 15, lq = lane >> 4;
    const unsigned aswz = (unsigned)((lrow & 7) << 4);
    const int fragoff = (lq * 256 + wave * 64 + lrow) * 8;   // global fragment-major
    unsigned short* swp = sW + wave * 4096;                  // wave-private 8KB
    const int wfrag = (lq * 64 + lrow) * 8;                  // stripe-local frag base

    // ---- basex GEMM -> 8 named uint2 fragments (W direct from L2, one-shot)
    uint2 bx00, bx01, bx02, bx03, bx10, bx11, bx12, bx13;
    {
        f32x4 acc[2][4];
        #pragma unroll
        for (int m = 0; m < 2; ++m)
            #pragma unroll
            for (int n = 0; n < 4; ++n) { f32x4 z = {0.f,0.f,0.f,0.f}; acc[m][n] = z; }
        #pragma unroll
        for (int kk = 0; kk < 4; ++kk) {
            short8 bfr[4];
            #pragma unroll
            for (int n = 0; n < 4; ++n)
                bfr[n] = *(const short8*)(wsW + kk * 8192 + fragoff + n * 128);
            short8 a[2];
            int kb = (kk * 32 + lq * 8) * 2;
            #pragma unroll
            for (int m = 0; m < 2; ++m)
                a[m] = *(const short8*)((const char*)sS +
                        (((unsigned)((m * 16 + lrow) * 256 + kb)) ^ aswz));
            #pragma unroll
            for (int m = 0; m < 2; ++m)
                #pragma unroll
                for (int n = 0; n < 4; ++n)
                    acc[m][n] = __builtin_amdgcn_mfma_f32_16x16x32_bf16(a[m], bfr[n], acc[m][n], 0, 0, 0);
        }
        float bias0 = bfv[wave * 64 + 0 * 16 + lrow];
        float bias1 = bfv[wave * 64 + 1 * 16 + lrow];
        float bias2 = bfv[wave * 64 + 2 * 16 + lrow];
        float bias3 = bfv[wave * 64 + 3 * 16 + lrow];
        bx00 = packbx(acc[0][0], bias0); bx01 = packbx(acc[0][1], bias1);
        bx02 = packbx(acc[0][2], bias2); bx03 = packbx(acc[0][3], bias3);
        bx10 = packbx(acc[1][0], bias0); bx11 = packbx(acc[1][1], bias1);
        bx12 = packbx(acc[1][2], bias2); bx13 = packbx(acc[1][3], bias3);
    }
    float Areg[4];
    #pragma unroll
    for (int n = 0; n < 4; ++n) Areg[n] = Aparam[wave * 64 + n * 16 + lrow];
    const float inv_tau = 1.0f / log1pf(expf(tau[0]));
    __syncthreads();   // sS (x) consumed

    const unsigned short* wstep = wsW + 4 * 8192;   // slices 4..19

// wave-private async stage of slice KK's 64-col stripe into buf B (4x1KB chunks)
#define ASYNCW(KK, B)                                                          \
    {   const unsigned short* gsrc = wstep + (KK) * 8192 + (wave * 64 + lane) * 8; \
        unsigned short* ldst = swp + (B) * 2048 + lane * 8;                    \
        gload_lds16(gsrc + 0 * 2048, ldst + 0 * 512);                          \
        gload_lds16(gsrc + 1 * 2048, ldst + 1 * 512);                          \
        gload_lds16(gsrc + 2 * 2048, ldst + 2 * 512);                          \
        gload_lds16(gsrc + 3 * 2048, ldst + 3 * 512);   }
// wave-level drain of in-flight stages (no barrier): rule-18 discipline
#define WAITW()                                                                \
    {   asm volatile("s_waitcnt vmcnt(0)" ::: "memory");                       \
        __builtin_amdgcn_sched_barrier(0);   }

    for (int t = 0; t < 6; ++t) {
        // stage slice 0 (drained by the phase-B __syncthreads vmcnt(0))
        ASYNCW(0, 0)

        // phase B: alpha/beta recurrence + sync -> sS (named-reg state)
        bchunk(0, aA, bA, sS, sH, tid, prow, pswz, pIdx, rsL);
        bchunk(1, aB, bB, sS, sH, tid, prow, pswz, pIdx, rsL);
        bchunk(2, aC, bC, sS, sH, tid, prow, pswz, pIdx, rsL);
        bchunk(3, aD, bD, sS, sH, tid, prow, pswz, pIdx, rsL);
        bchunk(4, aE, bE, sS, sH, tid, prow, pswz, pIdx, rsL);
        bchunk(5, aF, bF, sS, sH, tid, prow, pswz, pIdx, rsL);
        bchunk(6, aG, bG, sS, sH, tid, prow, pswz, pIdx, rsL);
        bchunk(7, aH, bH, sS, sH, tid, prow, pswz, pIdx, rsL);
        __syncthreads();   // sync tile visible; slice-0 stages drained

        // GEMM: [h | sync] (32x512) @ [Wfh|Wm]^T — BARRIER-FREE kk loop
        f32x4 acc[2][4];
        #pragma unroll
        for (int m = 0; m < 2; ++m)
            #pragma unroll
            for (int n = 0; n < 4; ++n) { f32x4 z = {0.f,0.f,0.f,0.f}; acc[m][n] = z; }

        #pragma unroll 1
        for (int kk = 0; kk < 16; ++kk) {
            if (kk < 15) { ASYNCW(kk + 1, (kk + 1) & 1) }   // wave-private dbuf
            const unsigned short* wb = swp + (kk & 1) * 2048;
            const char* srcA = (kk < 8) ? (const char*)sH : (const char*)sS;
            int kb = ((kk & 7) * 32 + lq * 8) * 2;
            short8 a0 = *(const short8*)(srcA + (((unsigned)((0 * 16 + lrow) * 512 + kb)) ^ aswz));
            short8 a1 = *(const short8*)(srcA + (((unsigned)((1 * 16 + lrow) * 512 + kb)) ^ aswz));
            short8 b0 = *(const short8*)(wb + wfrag + 0 * 128);
            short8 b1 = *(const short8*)(wb + wfrag + 1 * 128);
            short8 b2 = *(const short8*)(wb + wfrag + 2 * 128);
            short8 b3 = *(const short8*)(wb + wfrag + 3 * 128);
            acc[0][0] = __builtin_amdgcn_mfma_f32_16x16x32_bf16(a0, b0, acc[0][0], 0, 0, 0);
            acc[0][1] = __builtin_amdgcn_mfma_f32_16x16x32_bf16(a0, b1, acc[0][1], 0, 0, 0);
            acc[0][2] = __builtin_amdgcn_mfma_f32_16x16x32_bf16(a0, b2, acc[0][2], 0, 0, 0);
            acc[0][3] = __builtin_amdgcn_mfma_f32_16x16x32_bf16(a0, b3, acc[0][3], 0, 0, 0);
            acc[1][0] = __builtin_amdgcn_mfma_f32_16x16x32_bf16(a1, b0, acc[1][0], 0, 0, 0);
            acc[1][1] = __builtin_amdgcn_mfma_f32_16x16x32_bf16(a1, b1, acc[1][1], 0, 0, 0);
            acc[1][2] = __builtin_amdgcn_mfma_f32_16x16x32_bf16(a1, b2, acc[1][2], 0, 0, 0);
            acc[1][3] = __builtin_amdgcn_mfma_f32_16x16x32_bf16(a1, b3, acc[1][3], 0, 0, 0);
            if (kk < 15) { WAITW() }   // next iter reads the staged buffer
        }
        __syncthreads();   // all GEMM reads of sH done before epilogue rewrites it

        // epilogue: hu + fused speculative h update, norm partial
        float tsum = 0.0f;
        tsum += epifrag(0, 0, acc[0][0], bx00, sH, lq, lrow, wave, Areg[0], inv_tau);
        tsum += epifrag(0, 1, acc[0][1], bx01, sH, lq, lrow, wave, Areg[1], inv_tau);
        tsum += epifrag(0, 2, acc[0][2], bx02, sH, lq, lrow, wave, Areg[2], inv_tau);
        tsum += epifrag(0, 3, acc[0][3], bx03, sH, lq, lrow, wave, Areg[3], inv_tau);
        tsum += epifrag(1, 0, acc[1][0], bx10, sH, lq, lrow, wave, Areg[0], inv_tau);
        tsum += epifrag(1, 1, acc[1][1], bx11, sH, lq, lrow, wave, Areg[1], inv_tau);
        tsum += epifrag(1, 2, acc[1][2], bx12, sH, lq, lrow, wave, Areg[2], inv_tau);
        tsum += epifrag(1, 3, acc[1][3], bx13, sH, lq, lrow, wave, Areg[3], inv_tau);
        #pragma unroll
        for (int d = 32; d >= 1; d >>= 1) tsum += __shfl_down(tsum, d);
        if (lane == 0) red[wave] = tsum;
        __syncthreads();   // red + sH updates visible for next phase B
        if (tid == 0) atomicAdd(&norms_spec[t], red[0] + red[1] + red[2] + red[3]);
    }
#undef ASYNCW
#undef WAITW

    // ---- speculative outputs (f32); valid iff no break would have fired
    #pragma unroll
    for (int k = 0; k < 4; ++k) {
        int c = (tid & 7) * 8 + k * 64;
        uint4 hv = *(const uint4*)((const char*)sH + (((unsigned)(prow * 512 + c * 2)) ^ pswz));
        float hf[8];
        unpack8(hv, hf);
        int off = (r0 + prow) * 256 + c;
        *(float4*)(out + off)     = make_float4(hf[0], hf[1], hf[2], hf[3]);
        *(float4*)(out + off + 4) = make_float4(hf[4], hf[5], hf[6], hf[7]);
    }
    *(float4*)(out + 8388608 + cbase + 0 * 32) = aA;
    *(float4*)(out + 8388608 + cbase + 1 * 32) = aB;
    *(float4*)(out + 8388608 + cbase + 2 * 32) = aC;
    *(float4*)(out + 8388608 + cbase + 3 * 32) = aD;
    *(float4*)(out + 8388608 + cbase + 4 * 32) = aE;
    *(float4*)(out + 8388608 + cbase + 5 * 32) = aF;
    *(float4*)(out + 8388608 + cbase + 6 * 32) = aG;
    *(float4*)(out + 8388608 + cbase + 7 * 32) = aH;
    *(float4*)(out + 16777216 + cbase + 0 * 32) = bA;
    *(float4*)(out + 16777216 + cbase + 1 * 32) = bB;
    *(float4*)(out + 16777216 + cbase + 2 * 32) = bC;
    *(float4*)(out + 16777216 + cbase + 3 * 32) = bD;
    *(float4*)(out + 16777216 + cbase + 4 * 32) = bE;
    *(float4*)(out + 16777216 + cbase + 5 * 32) = bF;
    *(float4*)(out + 16777216 + cbase + 6 * 32) = bG;
    *(float4*)(out + 16777216 + cbase + 7 * 32) = bH;
    if (bid == 0 && tid == 0) out[25165824] = 5.0f;
}

// ---------------------------------------------------------------------------
// k_check: speculation valid iff no break at steps 3,4,5.
// ---------------------------------------------------------------------------
__global__ void k_check(const float* __restrict__ norms_spec, int* __restrict__ flag) {
    if (threadIdx.x == 0 && blockIdx.x == 0) {
        float thr = 0.01f * 8388608.0f;
        int ok = (norms_spec[3] >= thr) && (norms_spec[4] >= thr) && (norms_spec[5] >= thr);
        *flag = ok;
    }
}

// ===========================================================================
// FALLBACK (early-exit when *flag != 0): round-5 proven kernel set.
// ===========================================================================
struct StepCtl { bool run; bool upd; float factor; };
__device__ __forceinline__ StepCtl step_ctl(const float* norms, int t) {
    bool done = false, done_prev = false, brk_prev = false;
    for (int s = 0; s < t; ++s) {
        bool brk = false;
        if (!done) {
            float nm = norms[s] * (1.0f / 8388608.0f);
            brk = (s >= 3) && (nm < 0.01f);
        }
        if (s == t - 1) { done_prev = done; brk_prev = brk; }
        done = done || brk;
    }
    StepCtl c;
    c.upd = (t > 0) && !done_prev;
    c.factor = brk_prev ? 1.0f : 2.0f;
    c.run = !done;
    return c;
}

__global__ __launch_bounds__(256) void k_fbinit(const float* __restrict__ h0,
                                                const float* __restrict__ beta0,
                                                unsigned short* __restrict__ h_ws,
                                                unsigned short* __restrict__ b0b,
                                                const int* __restrict__ flag) {
    if (*flag) return;
    int b = blockIdx.x, tid = threadIdx.x;
    if (b < 4096) {
        int idx = b * 2048 + tid * 8;
        float4 v0 = *(const float4*)(h0 + idx), v1 = *(const float4*)(h0 + idx + 4);
        float vf[8] = {v0.x, v0.y, v0.z, v0.w, v1.x, v1.y, v1.z, v1.w};
        *(uint4*)(h_ws + idx) = pack8(vf);
    } else {
        int idx = (b - 4096) * 2048 + tid * 8;
        float4 v0 = *(const float4*)(beta0 + idx), v1 = *(const float4*)(beta0 + idx + 4);
        float vf[8] = {v0.x, v0.y, v0.z, v0.w, v1.x, v1.y, v1.z, v1.w};
        *(uint4*)(b0b + idx) = pack8(vf);
    }
}

__global__ __launch_bounds__(256, 4) void k_basex(const float* __restrict__ x,
                                                  const float* __restrict__ bfv,
                                                  const unsigned short* __restrict__ wsW,
                                                  unsigned short* __restrict__ basex,
                                                  const int* __restrict__ flag) {
    if (*flag) return;
    __shared__ unsigned short sX[32 * 128];
    const int tid = threadIdx.x, r0 = blockIdx.x * 32;
    const int prow = tid >> 3;
    const unsigned pswz = (unsigned)((prow & 7) << 4);

    #pragma unroll
    for (int k = 0; k < 4; ++k) {
        int c = (tid & 7) * 4 + k * 32;
        float4 v = *(const float4*)(x + (r0 + prow) * 128 + c);
        uint2 pk;
        pk.x = (unsigned)f2b(v.x) | ((unsigned)f2b(v.y) << 16);
        pk.y = (unsigned)f2b(v.z) | ((unsigned)f2b(v.w) << 16);
        *(uint2*)((char*)sX + (((unsigned)(prow * 256 + c * 2)) ^ pswz)) = pk;
    }
    __syncthreads();

    const int wave = tid >> 6, lane = tid & 63, lrow = lane & 15, lq = lane >> 4;
    const unsigned aswz = (unsigned)((lrow & 7) << 4);
    const int fragoff = (lq * 256 + wave * 64 + lrow) * 8;

    f32x4 acc[2][4];
    #pragma unroll
    for (int m = 0; m < 2; ++m)
        #pragma unroll
        for (int n = 0; n < 4; ++n) { f32x4 z = {0.f,0.f,0.f,0.f}; acc[m][n] = z; }

    #pragma unroll
    for (int kk = 0; kk < 4; ++kk) {
        short8 bfr[4];
        #pragma unroll
        for (int n = 0; n < 4; ++n)
            bfr[n] = *(const short8*)(wsW + kk * 8192 + fragoff + n * 128);
        short8 a[2];
        int kb = (kk * 32 + lq * 8) * 2;
        #pragma unroll
        for (int m = 0; m < 2; ++m)
            a[m] = *(const short8*)((const char*)sX +
                    (((unsigned)((m * 16 + lrow) * 256 + kb)) ^ aswz));
        #pragma unroll
        for (int m = 0; m < 2; ++m)
            #pragma unroll
            for (int n = 0; n < 4; ++n)
                acc[m][n] = __builtin_amdgcn_mfma_f32_16x16x32_bf16(a[m], bfr[n], acc[m][n], 0, 0, 0);
    }

    #pragma unroll
    for (int n = 0; n < 4; ++n) {
        int col = wave * 64 + n * 16 + lrow;
        float bias = bfv[col];
        #pragma unroll
        for (int m = 0; m < 2; ++m)
            #pragma unroll
            for (int r = 0; r < 4; ++r) {
                int row = m * 16 + lq * 4 + r;
                basex[(r0 + row) * 256 + col] = f2b(acc[m][n][r] + bias);
            }
    }
}

__global__ __launch_bounds__(256, 4) void k_step(int t,
        unsigned short* __restrict__ h_ws, unsigned short* __restrict__ hu,
        const unsigned short* __restrict__ basex, const unsigned short* __restrict__ b0b,
        const unsigned short* __restrict__ wsW, const float* __restrict__ rs,
        float* __restrict__ norms,
        const float* __restrict__ alpha0, float* __restrict__ alpha_io,
        const int* __restrict__ idxl, const int* __restrict__ idxr,
        const float* __restrict__ Aparam, const float* __restrict__ tau,
        const int* __restrict__ flag) {
    if (*flag) return;
    __shared__ unsigned short sH[32 * 256];
    __shared__ unsigned short sA[32 * 256];
    __shared__ int   pIdx[256];
    __shared__ float rsL[256], btP[256], btS[256];
    __shared__ float red[4];

    const int tid = threadIdx.x;
    const int r0 = blockIdx.x * 32;

    StepCtl ctl = step_ctl(norms, t);
    if (!ctl.run && !ctl.upd) return;

    {
        float rr = rs[tid];
        rsL[tid]  = rr;
        pIdx[tid] = (idxl[tid] & 0xffff) | (idxr[tid] << 16);
        float p = 1.0f, ssum = 0.0f;
        for (int u = 0; u <= t; ++u) { ssum += p; p *= rr; }
        btP[tid] = p; btS[tid] = ssum;
    }

    const int prow = tid >> 3;
    const unsigned pswz = (unsigned)((prow & 7) << 4);

    #pragma unroll
    for (int k = 0; k < 4; ++k) {
        int c = (tid & 7) * 8 + k * 64;
        int off = (r0 + prow) * 256 + c;
        uint4 hv = *(const uint4*)(h_ws + off);
        if (ctl.upd) {
            uint4 uv = *(const uint4*)(hu + off);
            float hf[8], uf[8], nf[8];
            unpack8(hv, hf); unpack8(uv, uf);
            #pragma unroll
            for (int j = 0; j < 8; ++j) nf[j] = hf[j] + ctl.factor * uf[j];
            hv = pack8(nf);
            *(uint4*)(h_ws + off) = hv;
        }
        *(uint4*)((char*)sH + (((unsigned)(prow * 512 + c * 2)) ^ pswz)) = hv;
    }
    if (!ctl.run) return;
    __syncthreads();

    #pragma unroll
    for (int k = 0; k < 8; ++k) {
        int c = (tid & 7) * 4 + k * 32;
        int off = (r0 + prow) * 256 + c;
        float4 av = (t == 0) ? *(const float4*)(alpha0 + off)
                             : *(const float4*)(alpha_io + off);
        uint2 b0v = *(const uint2*)(b0b + off);
        float bb[4] = {b2f(b0v.x), b2f(b0v.x >> 16), b2f(b0v.y), b2f(b0v.y >> 16)};
        float aa[4] = {av.x, av.y, av.z, av.w};
        float sy[4];
        #pragma unroll
        for (int j = 0; j < 4; ++j) {
            int cj = c + j;
            int pr = pIdx[cj];
            float hl = b2f(*(const unsigned short*)((const char*)sH +
                       (((unsigned)(prow * 512 + (pr & 0xffff) * 2)) ^ pswz)));
            float hr = b2f(*(const unsigned short*)((const char*)sH +
                       (((unsigned)(prow * 512 + (pr >> 16) * 2)) ^ pswz)));
            float a_new = rsL[cj] * aa[j] + hl * hr;
            aa[j] = a_new;
            float bt = btP[cj] * bb[j] + btS[cj];
            sy[j] = a_new / (sqrtf(bt) + 1e-6f);
        }
        *(float4*)(alpha_io + off) = make_float4(aa[0], aa[1], aa[2], aa[3]);
        uint2 pk;
        pk.x = (unsigned)f2b(sy[0]) | ((unsigned)f2b(sy[1]) << 16);
        pk.y = (unsigned)f2b(sy[2]) | ((unsigned)f2b(sy[3]) << 16);
        *(uint2*)((char*)sA + (((unsigned)(prow * 512 + c * 2)) ^ pswz)) = pk;
    }
    __syncthreads();

    const int wave = tid >> 6, lane = tid & 63, lrow = lane & 15, lq = lane >> 4;
    const unsigned aswz = (unsigned)((lrow & 7) << 4);
    const int fragoff = (lq * 256 + wave * 64 + lrow) * 8;
    const unsigned short* wstep = wsW + 4 * 8192;

    f32x4 acc[2][4];
    #pragma unroll
    for (int m = 0; m < 2; ++m)
        #pragma unroll
        for (int n = 0; n < 4; ++n) { f32x4 z = {0.f,0.f,0.f,0.f}; acc[m][n] = z; }

    #pragma unroll 1
    for (int kk = 0; kk < 16; ++kk) {
        short8 bfr[4];
        #pragma unroll
        for (int n = 0; n < 4; ++n)
            bfr[n] = *(const short8*)(wstep + kk * 8192 + fragoff + n * 128);
        const char* src = (kk < 8) ? (const char*)sH : (const char*)sA;
        int kb = ((kk & 7) * 32 + lq * 8) * 2;
        short8 a[2];
        #pragma unroll
        for (int m = 0; m < 2; ++m)
            a[m] = *(const short8*)(src + (((unsigned)((m * 16 + lrow) * 512 + kb)) ^ aswz));
        #pragma unroll
        for (int m = 0; m < 2; ++m)
            #pragma unroll
            for (int n = 0; n < 4; ++n)
                acc[m][n] = __builtin_amdgcn_mfma_f32_16x16x32_bf16(a[m], bfr[n], acc[m][n], 0, 0, 0);
    }

    const float inv_tau = 1.0f / log1pf(expf(tau[0]));
    float Areg[4];
    #pragma unroll
    for (int n = 0; n < 4; ++n) Areg[n] = Aparam[wave * 64 + n * 16 + lrow];
    float tsum = 0.0f;
    #pragma unroll
    for (int m = 0; m < 2; ++m)
        #pragma unroll
        for (int n = 0; n < 4; ++n) {
            int col = wave * 64 + n * 16 + lrow;
            #pragma unroll
            for (int r = 0; r < 4; ++r) {
                int row = m * 16 + lq * 4 + r;
                int off = (r0 + row) * 256 + col;
                float arg = acc[m][n][r] + b2f(basex[off]);
                float s = __sinf(arg);
                float fv = s * s;
                float hv = b2f(*(const unsigned short*)((const char*)sH +
                           (((unsigned)(row * 512 + col * 2)) ^ ((unsigned)((row & 7) << 4)))));
                float dh = -hv * (inv_tau + fv) + Areg[n] * fv;
                float huv = 0.1f * dh;
                hu[off] = f2b(huv);
                tsum += fabsf(huv);
            }
        }
    #pragma unroll
    for (int d = 32; d >= 1; d >>= 1) tsum += __shfl_down(tsum, d);
    if (lane == 0) red[wave] = tsum;
    __syncthreads();
    if (tid == 0) atomicAdd(&norms[t], red[0] + red[1] + red[2] + red[3]);
}

__global__ __launch_bounds__(256) void k_final(const unsigned short* __restrict__ h_ws,
                                               const unsigned short* __restrict__ hu,
                                               const unsigned short* __restrict__ b0b,
                                               const float* __restrict__ rs,
                                               const float* __restrict__ norms,
                                               float* __restrict__ out,
                                               const int* __restrict__ flag) {
    if (*flag) return;
    bool done = false, exec5 = false;
    int last = 0;
    float f5 = 2.0f;
    for (int s = 0; s < 6; ++s) {
        if (!done) {
            last = s;
            float nm = norms[s] * (1.0f / 8388608.0f);
            bool brk = (s >= 3) && (nm < 0.01f);
            if (s == 5) { exec5 = true; f5 = brk ? 1.0f : 2.0f; }
            done = done || brk;
        }
    }
    int n_exec = last + 1;

    int base = (blockIdx.x * 256 + threadIdx.x) * 16;
    #pragma unroll
    for (int c8 = 0; c8 < 2; ++c8) {
        int off = base + c8 * 8;
        uint4 hv = *(const uint4*)(h_ws + off);
        float hf[8];
        unpack8(hv, hf);
        if (exec5) {
            uint4 uv = *(const uint4*)(hu + off);
            float uf[8];
            unpack8(uv, uf);
            #pragma unroll
            for (int j = 0; j < 8; ++j) hf[j] += f5 * uf[j];
        }
        *(float4*)(out + off)     = make_float4(hf[0], hf[1], hf[2], hf[3]);
        *(float4*)(out + off + 4) = make_float4(hf[4], hf[5], hf[6], hf[7]);

        uint4 bv = *(const uint4*)(b0b + off);
        float bb[8];
        unpack8(bv, bb);
        int c0 = off & 255;
        float bo[8];
        #pragma unroll
        for (int j = 0; j < 8; ++j) {
            float rr = rs[c0 + j];
            float p = 1.0f, ss = 0.0f;
            for (int u = 0; u < n_exec; ++u) { ss += p; p *= rr; }
            bo[j] = p * bb[j] + ss;
        }
        *(float4*)(out + 16777216 + off)     = make_float4(bo[0], bo[1], bo[2], bo[3]);
        *(float4*)(out + 16777216 + off + 4) = make_float4(bo[4], bo[5], bo[6], bo[7]);
    }
    if (blockIdx.x == 0 && threadIdx.x == 0) out[25165824] = (float)last;
}

// ---------------------------------------------------------------------------
extern "C" void kernel_launch(void* const* d_in, const int* in_sizes, int n_in,
                              void* d_out, int out_size, void* d_ws, size_t ws_size,
                              hipStream_t stream) {
    const float* x      = (const float*)d_in[0];
    const float* h0     = (const float*)d_in[1];
    const float* alpha0 = (const float*)d_in[2];
    const float* beta0  = (const float*)d_in[3];
    const float* Wf     = (const float*)d_in[4];
    const float* bfv    = (const float*)d_in[5];
    const float* tau    = (const float*)d_in[6];
    const float* rparam = (const float*)d_in[7];
    const float* Aparam = (const float*)d_in[8];
    const float* Wm     = (const float*)d_in[9];
    const int* idxl     = (const int*)d_in[10];
    const int* idxr     = (const int*)d_in[11];

    char* ws = (char*)d_ws;
    unsigned short* h_ws   = (unsigned short*)(ws + 0);           // bf16 16.78MB (fallback)
    unsigned short* hu     = (unsigned short*)(ws + 16777216);    // bf16 16.78MB (fallback)
    unsigned short* basex  = (unsigned short*)(ws + 33554432);    // bf16 16.78MB (fallback)
    unsigned short* b0b    = (unsigned short*)(ws + 50331648);    // bf16 16.78MB (fallback)
    unsigned short* wsW    = (unsigned short*)(ws + 67108864);    // bf16 320KB
    float*          rs     = (float*)(ws + 67436544);             // f32 [256]
    float*          n_spec = (float*)(ws + 67437568);             // f32 [8]
    float*          n_fb   = (float*)(ws + 67437600);             // f32 [8]
    int*            flag   = (int*)(ws + 67437632);               // int

    float* out = (float*)d_out;
    float* alpha_io = out + 8388608;   // fallback writes alpha in place

    k_winit<<<81, 256, 0, stream>>>(Wf, Wm, rparam, wsW, rs, n_spec, n_fb);
    k_spec<<<1024, 256, 0, stream>>>(x, h0, alpha0, beta0, wsW, rs, bfv, tau,
                                     Aparam, idxl, idxr, n_spec, out);
    k_check<<<1, 64, 0, stream>>>(n_spec, flag);
    // fallback chain (early-exits when speculation verified)
    k_fbinit<<<8192, 256, 0, stream>>>(h0, beta0, h_ws, b0b, flag);
    k_basex<<<1024, 256, 0, stream>>>(x, bfv, wsW, basex, flag);
    for (int t = 0; t < 6; ++t)
        k_step<<<1024, 256, 0, stream>>>(t, h_ws, hu, basex, b0b, wsW, rs, n_fb,
                                         alpha0, alpha_io, idxl, idxr, Aparam, tau, flag);
    k_final<<<2048, 256, 0, stream>>>(h_ws, hu, b0b, rs, n_fb, out, flag);
}